// Round 17
// baseline (184.711 us; speedup 1.0000x reference)
//
#include <hip/hip_runtime.h>
#include <hip/hip_bf16.h>
#include <stdint.h>

// Problem constants
constexpr int BB = 4, TT = 2048, CC = 1024, HH = 16, DD = 64;

typedef __bf16 bf16_t;
typedef bf16_t bf16x8 __attribute__((ext_vector_type(8)));
typedef float f32x4 __attribute__((ext_vector_type(4)));

// Native cast: compiler emits v_cvt_pk_bf16_f32 for adjacent pairs (RNE).
__device__ __forceinline__ unsigned short f2bf(float f) {
    union { __bf16 h; unsigned short u; } v;
    v.h = (__bf16)f;
    return v.u;
}

__device__ __forceinline__ f32x4 mfma16(bf16x8 a, bf16x8 b, f32x4 c) {
    return __builtin_amdgcn_mfma_f32_16x16x32_bf16(a, b, c, 0, 0, 0);
}

#define LOAD_LDS16(g, l)                                                      \
    __builtin_amdgcn_global_load_lds(                                         \
        (const __attribute__((address_space(1))) void*)(g),                   \
        (__attribute__((address_space(3))) void*)(l), 16, 0, 0)

// ---------------- fused f32 -> bf16 convert for all 3 arrays ----------------
__global__ __launch_bounds__(256) void cvt_all(
    const float* __restrict__ a, long na,    // quads
    const float* __restrict__ b, long nb,    // quads
    const float* __restrict__ c, long nc,    // quads
    unsigned short* __restrict__ oa, unsigned short* __restrict__ ob,
    unsigned short* __restrict__ oc) {
    const long ntot = na + nb + nc;
    long i = (long)blockIdx.x * blockDim.x + threadIdx.x;
    const long stride = (long)gridDim.x * blockDim.x;
    for (; i < ntot; i += stride) {
        const float* src;
        unsigned short* dst;
        long q = i;
        if (q < na) { src = a; dst = oa; }
        else if (q < na + nb) { q -= na; src = b; dst = ob; }
        else { q -= na + nb; src = c; dst = oc; }
        float4 v = *(const float4*)(src + q * 4);
        ushort4 o;
        o.x = f2bf(v.x); o.y = f2bf(v.y); o.z = f2bf(v.z); o.w = f2bf(v.w);
        *(ushort4*)(dst + q * 4) = o;
    }
}

// ---------------- GEMM: C[m,n] = sum_k A[m,k]*Bw[n,k] + bias[n] ----------------
// m97 structure: 128x128 tile, BK=32, 4 waves, global_load_lds(16B), dbuf LDS.
// __launch_bounds__(256,3): pin 3 blocks/CU (R10-verified). Do not restructure
// the K-loop (R8/R11 deep-pipeline rewrites both lost at K=1024).
// MODE 0 epilogue: q scaled by 0.125*log2e (log2-domain softmax downstream).
//   which==2 (v) blocks: LDS-transpose epilogue (R16, -24 us) — coalesced 16B
//   v^T stores via [2][64][136] d-major tile with chunk XOR c^=d&7.
// MODE 1: f32 out[m*N+n] (coalesced, direct).
template <int MODE>
__global__ __launch_bounds__(256, 3) void gemm_bt(
    const unsigned short* __restrict__ A,    // [M][K] bf16
    const unsigned short* __restrict__ Bw,   // [N][K] bf16
    const float* __restrict__ bias,          // [N]
    unsigned short* __restrict__ qb, unsigned short* __restrict__ kb,
    unsigned short* __restrict__ vtb, float* __restrict__ outf,
    int M, int N, int K) {
    __shared__ __align__(16) unsigned short smem[17408];
    unsigned short* Asb = smem;
    unsigned short* Bsb = smem + 8192;
    const int tid = threadIdx.x;
    const int w = tid >> 6, lane = tid & 63;
    const int g = lane >> 4, q16 = lane & 15;
    const int wr = w >> 1, wc = w & 1;
    const int mbase = blockIdx.x * 128;
    const int nbase = blockIdx.y * 128;
    const int srow = lane >> 2;
    const int scol = (lane & 3) * 8;

    f32x4 acc[4][4];
#pragma unroll
    for (int i = 0; i < 4; ++i)
#pragma unroll
        for (int j = 0; j < 4; ++j) acc[i][j] = (f32x4){0.f, 0.f, 0.f, 0.f};

    const int nk = K >> 5;

    auto stage = [&](int buf, int t) {
        const int k0 = t << 5;
#pragma unroll
        for (int ii = 0; ii < 2; ++ii) {
            const int i = w + ii * 4;
            const unsigned short* ga =
                A + (long)(mbase + i * 16 + srow) * K + k0 + scol;
            LOAD_LDS16(ga, &Asb[buf * 4096 + i * 512]);
            const unsigned short* gb =
                Bw + (long)(nbase + i * 16 + srow) * K + k0 + scol;
            LOAD_LDS16(gb, &Bsb[buf * 4096 + i * 512]);
        }
    };

    stage(0, 0);
    __syncthreads();
    int cur = 0;
    for (int t = 0; t < nk; ++t) {
        if (t + 1 < nk) stage(cur ^ 1, t + 1);
        bf16x8 af[4], bfr[4];
#pragma unroll
        for (int mi = 0; mi < 4; ++mi)
            af[mi] = *(const bf16x8*)&Asb[cur * 4096 +
                                          (wr * 64 + mi * 16 + q16) * 32 + 8 * g];
#pragma unroll
        for (int ni = 0; ni < 4; ++ni)
            bfr[ni] = *(const bf16x8*)&Bsb[cur * 4096 +
                                           (wc * 64 + ni * 16 + q16) * 32 + 8 * g];
#pragma unroll
        for (int mi = 0; mi < 4; ++mi)
#pragma unroll
            for (int ni = 0; ni < 4; ++ni)
                acc[mi][ni] = mfma16(af[mi], bfr[ni], acc[mi][ni]);
        __syncthreads();
        cur ^= 1;
    }

    if (MODE == 0 && (nbase >> 10) == 2) {
        // ---- v-block: LDS transpose epilogue (As/Bs dead after final barrier)
        const int bb = mbase >> 11, t0 = mbase & 2047;
        const int h0 = (nbase & 1023) >> 6;
#pragma unroll
        for (int mi = 0; mi < 4; ++mi) {
#pragma unroll
            for (int ni = 0; ni < 4; ++ni) {
                const int nl = wc * 64 + ni * 16 + q16;   // 0..127
                const int hh = nl >> 6, d = nl & 63;
                const float bv = bias[nbase + nl];
                ushort4 pk;
                pk.x = f2bf(acc[mi][ni][0] + bv);
                pk.y = f2bf(acc[mi][ni][1] + bv);
                pk.z = f2bf(acc[mi][ni][2] + bv);
                pk.w = f2bf(acc[mi][ni][3] + bv);
                const int tb = wr * 64 + mi * 16 + 4 * g;  // t' of r=0
                const int cp = (tb >> 3) ^ (d & 7);        // chunk XOR swizzle
                const int pos = cp * 8 + (tb & 7);
                *(ushort4*)&smem[hh * 8704 + d * 136 + pos] = pk;
            }
        }
        __syncthreads();
#pragma unroll
        for (int it = 0; it < 8; ++it) {
            const int task = it * 256 + tid;
            const int hh = task >> 10, d = (task >> 4) & 63, cr = task & 15;
            const int cp = cr ^ (d & 7);
            uint4 v4 = *(const uint4*)&smem[hh * 8704 + d * 136 + cp * 8];
            const long off =
                ((long)(bb * HH + h0 + hh) * DD + d) * TT + t0 + cr * 8;
            *(uint4*)&vtb[off] = v4;
        }
        return;
    }

#pragma unroll
    for (int mi = 0; mi < 4; ++mi) {
#pragma unroll
        for (int ni = 0; ni < 4; ++ni) {
            const int n = nbase + wc * 64 + ni * 16 + q16;
            const float bv = bias[n];
#pragma unroll
            for (int r = 0; r < 4; ++r) {
                const int m = mbase + wr * 64 + mi * 16 + 4 * g + r;
                const float val = acc[mi][ni][r] + bv;
                if (MODE == 0) {
                    const int rem = n & 1023;
                    const int h = rem >> 6, d = rem & 63;
                    const int b = m >> 11, t = m & 2047;
                    const long bh = (long)(b * HH + h);
                    if ((n >> 10) == 0)  // 0.125*log2e: log2-domain softmax
                        qb[(bh * TT + t) * DD + d] =
                            f2bf(val * 0.18033688011112042f);
                    else
                        kb[(bh * TT + t) * DD + d] = f2bf(val);
                } else {
                    outf[(long)m * N + n] = val;
                }
            }
        }
    }
}

// ------ causal flash attention (2 q-sets/wave: K/V LDS reads amortized) -----
// grid: flat 1024 blocks, XCD-swizzled (8 bh/XCD); LPT (bxp = 15-(swz&15)).
// QBLK=128: wave owns 32 q-rows as sets {qb0=128bxp+16w, qb1=qb0+64}.
// Per tile: K fragments ds_read ONCE (regs, both sets' QK), V fragments
// ds_read ONCE (merged PV: each bv pair feeds 4 MFMAs = 2 sets x 2) ->
// K/V LDS traffic per q-row HALVED vs R16 (LDS BW was ~half the runtime).
// Set0 live iff kt <= 2bxp (skips its final fully-masked tile; uniform).
// Sequencing caps VGPR: QK0 -> SM0->pa0 (p0 dies) -> QK1 (K regs live) ->
// SM1->pa1 -> merged PV. plds reused sequentially per set (in-order LDS).
// Softmax: R15 shfl-free (in-lane defer vote, per-lane partial denominator),
// log2-domain. (256,3): cap 170 VGPR, 3 blocks/CU.
__global__ __launch_bounds__(256, 3) void attn_fwd(
    const unsigned short* __restrict__ qb, const unsigned short* __restrict__ kb,
    const unsigned short* __restrict__ vtb, unsigned short* __restrict__ attb) {
    __shared__ __align__(16) unsigned short Ks[2][64 * 64];
    __shared__ __align__(16) unsigned short Vs[2][64 * 64];
    __shared__ __align__(16) unsigned short plds[4][16 * 64];
    const int tid = threadIdx.x;
    const int w = tid >> 6, lane = tid & 63;
    const int g = lane >> 4, q16 = lane & 15;
    const int bid = blockIdx.x;
    const int swz = (bid & 7) * 128 + (bid >> 3);   // 1024 % 8 == 0: bijective
    const int bxp = 15 - (swz & 15);                // LPT: big first
    const int bh = swz >> 4;
    const int b = bh >> 4, h = bh & 15;
    const int qs0 = bxp * 128 + w * 16;             // set0 rows
    const int qs1 = qs0 + 64;                       // set1 rows

    const unsigned short* Q = qb + (long)bh * TT * DD;
    const unsigned short* Kp = kb + (long)bh * TT * DD;
    const unsigned short* Vt = vtb + (long)bh * DD * TT;

    const int srow = tid >> 3;                       // 0..31
    const int ssl = ((tid & 7) ^ (srow & 7)) * 8;    // swizzled col (shorts)
    unsigned short* kdst0 = &Ks[0][0] + w * 512;     // wave-uniform dests
    unsigned short* vdst0 = &Vs[0][0] + w * 512;

    auto stageKV = [&](int buf, int kt) {
        const long kb0 = (long)kt * 64;
        const unsigned short* gk = Kp + (kb0 + srow) * DD + ssl;
        const unsigned short* gv = Vt + (long)srow * TT + kb0 + ssl;
        unsigned short* kd = kdst0 + buf * 4096;
        unsigned short* vd = vdst0 + buf * 4096;
        LOAD_LDS16(gk, kd);
        LOAD_LDS16(gk + 32l * DD, kd + 2048);
        LOAD_LDS16(gv, vd);
        LOAD_LDS16(gv + 32l * TT, vd + 2048);
    };

    bf16x8 aq[2][2];
    aq[0][0] = *(const bf16x8*)&Q[(qs0 + q16) * DD + 8 * g];
    aq[0][1] = *(const bf16x8*)&Q[(qs0 + q16) * DD + 32 + 8 * g];
    aq[1][0] = *(const bf16x8*)&Q[(qs1 + q16) * DD + 8 * g];
    aq[1][1] = *(const bf16x8*)&Q[(qs1 + q16) * DD + 32 + 8 * g];

    f32x4 acc[2][4];
#pragma unroll
    for (int js = 0; js < 2; ++js)
#pragma unroll
        for (int i = 0; i < 4; ++i) acc[js][i] = (f32x4){0.f, 0.f, 0.f, 0.f};
    float mrow[2] = {-1e30f, -1e30f}, lrow[2] = {0.f, 0.f};

    const int slot0 = (g ^ (q16 & 7)) << 3;
    const int nkt = 2 * bxp + 2;
    stageKV(0, 0);
    __syncthreads();
    int cur = 0;
    for (int kt = 0; kt < nkt; ++kt) {
        if (kt + 1 < nkt) stageKV(cur ^ 1, kt + 1);
        const int kbase = kt * 64;
        const bool live0 = (kt <= 2 * bxp);  // block-uniform
        bf16x8 pa[2][2];

        // ---- K fragments once (shared by both sets)
        bf16x8 bk[4][2];
#pragma unroll
        for (int s = 0; s < 4; ++s) {
            const int kr = (16 * s + q16) * 64;
            bk[s][0] = *(const bf16x8*)&Ks[cur][kr + slot0];
            bk[s][1] = *(const bf16x8*)&Ks[cur][kr + (slot0 ^ 32)];
        }

        // ---- per-set QK + softmax + pack (set0 first; p dies before set1)
#pragma unroll
        for (int js = 0; js < 2; ++js) {
            if (js == 0 && !live0) continue;
            f32x4 p[4];
#pragma unroll
            for (int s = 0; s < 4; ++s) p[s] = (f32x4){0.f, 0.f, 0.f, 0.f};
            __builtin_amdgcn_s_setprio(1);
#pragma unroll
            for (int s = 0; s < 4; ++s) {
                p[s] = mfma16(bk[s][0], aq[js][0], p[s]);
                p[s] = mfma16(bk[s][1], aq[js][1], p[s]);
            }
            __builtin_amdgcn_s_setprio(0);
            const int qrow = (js ? qs1 : qs0) + q16;
            const int mtile = 2 * bxp + js;  // diagonal tile of this set
            if (kt == mtile) {
#pragma unroll
                for (int s = 0; s < 4; ++s)
#pragma unroll
                    for (int r = 0; r < 4; ++r)
                        if (kbase + 16 * s + 4 * g + r > qrow) p[s][r] = -1e30f;
            }
            float t = fmaxf(fmaxf(p[0][0], p[0][1]), fmaxf(p[0][2], p[0][3]));
#pragma unroll
            for (int s = 1; s < 4; ++s)
                t = fmaxf(t, fmaxf(fmaxf(p[s][0], p[s][1]),
                                   fmaxf(p[s][2], p[s][3])));
            if (__all(t - mrow[js] <= 11.541560327111708f)) {  // 8*log2e
                float ssum = 0.f;
#pragma unroll
                for (int s = 0; s < 4; ++s)
#pragma unroll
                    for (int r = 0; r < 4; ++r) {
                        p[s][r] = __builtin_amdgcn_exp2f(p[s][r] - mrow[js]);
                        ssum += p[s][r];
                    }
                lrow[js] += ssum;  // per-lane partial
            } else {
                t = fmaxf(t, __shfl_xor(t, 16));
                t = fmaxf(t, __shfl_xor(t, 32));
                const float nm = fmaxf(mrow[js], t);
                const float fs = __builtin_amdgcn_exp2f(mrow[js] - nm);
                mrow[js] = nm;
                float ssum = 0.f;
#pragma unroll
                for (int s = 0; s < 4; ++s)
#pragma unroll
                    for (int r = 0; r < 4; ++r) {
                        p[s][r] = __builtin_amdgcn_exp2f(p[s][r] - nm);
                        ssum += p[s][r];
                    }
                lrow[js] = lrow[js] * fs + ssum;
                float fr[4];
#pragma unroll
                for (int r = 0; r < 4; ++r) fr[r] = __shfl(fs, 4 * g + r);
#pragma unroll
                for (int ni = 0; ni < 4; ++ni)
#pragma unroll
                    for (int r = 0; r < 4; ++r) acc[js][ni][r] *= fr[r];
            }
            // pack P -> plds (per-wave, sequential reuse) -> pa[js]
#pragma unroll
            for (int s = 0; s < 4; ++s) {
                ushort4 pk;
                pk.x = f2bf(p[s][0]); pk.y = f2bf(p[s][1]);
                pk.z = f2bf(p[s][2]); pk.w = f2bf(p[s][3]);
                const int Gp = ((2 * s + (g >> 1)) ^ (q16 & 7)) * 8 + (g & 1) * 4;
                *(ushort4*)&plds[w][q16 * 64 + Gp] = pk;
            }
            pa[js][0] = *(const bf16x8*)&plds[w][q16 * 64 + slot0];
            pa[js][1] = *(const bf16x8*)&plds[w][q16 * 64 + (slot0 ^ 32)];
        }

        // ---- merged PV: V fragments once, feed both sets
        __builtin_amdgcn_s_setprio(1);
#pragma unroll
        for (int ni = 0; ni < 4; ++ni) {
            const int vr = (ni * 16 + q16) * 64;
            bf16x8 bv0 = *(const bf16x8*)&Vs[cur][vr + slot0];
            bf16x8 bv1 = *(const bf16x8*)&Vs[cur][vr + (slot0 ^ 32)];
            if (live0) {
                acc[0][ni] = mfma16(pa[0][0], bv0, acc[0][ni]);
                acc[0][ni] = mfma16(pa[0][1], bv1, acc[0][ni]);
            }
            acc[1][ni] = mfma16(pa[1][0], bv0, acc[1][ni]);
            acc[1][ni] = mfma16(pa[1][1], bv1, acc[1][ni]);
        }
        __builtin_amdgcn_s_setprio(0);
        __syncthreads();
        cur ^= 1;
    }
    // one cross-lane denominator reduction per set
#pragma unroll
    for (int js = 0; js < 2; ++js) {
        float l = lrow[js];
        l += __shfl_xor(l, 16);
        l += __shfl_xor(l, 32);
        float inv[4];
#pragma unroll
        for (int r = 0; r < 4; ++r) inv[r] = 1.0f / __shfl(l, 4 * g + r);
        const int qsb = js ? qs1 : qs0;
#pragma unroll
        for (int ni = 0; ni < 4; ++ni)
#pragma unroll
            for (int r = 0; r < 4; ++r) {
                const int q = qsb + 4 * g + r;
                const int d = ni * 16 + q16;
                attb[(((long)b * TT + q) * HH + h) * DD + d] =
                    f2bf(acc[js][ni][r] * inv[r]);
            }
    }
}

extern "C" void kernel_launch(void* const* d_in, const int* in_sizes, int n_in,
                              void* d_out, int out_size, void* d_ws, size_t ws_size,
                              hipStream_t stream) {
    const float* x = (const float*)d_in[0];
    const float* Wqkv = (const float*)d_in[1];
    const float* bqkv = (const float*)d_in[2];
    const float* Wproj = (const float*)d_in[3];
    const float* bproj = (const float*)d_in[4];
    float* out = (float*)d_out;

    char* ws = (char*)d_ws;
    unsigned short* xb = (unsigned short*)(ws);                  // 16 MB (reused as attb)
    unsigned short* wqkvb = (unsigned short*)(ws + (16l << 20)); // 6 MB
    unsigned short* wprojb = (unsigned short*)(ws + (22l << 20));// 2 MB
    unsigned short* qb = (unsigned short*)(ws + (24l << 20));    // 16 MB
    unsigned short* kb = (unsigned short*)(ws + (40l << 20));    // 16 MB
    unsigned short* vtb = (unsigned short*)(ws + (56l << 20));   // 16 MB
    unsigned short* attb = xb;  // x dead after QKV GEMM; reuse

    cvt_all<<<2048, 256, 0, stream>>>(
        x, (long)BB * TT * CC / 4, Wqkv, (long)3 * CC * CC / 4, Wproj,
        (long)CC * CC / 4, xb, wqkvb, wprojb);

    gemm_bt<0><<<dim3(64, 24), 256, 0, stream>>>(xb, wqkvb, bqkv, qb, kb, vtb,
                                                 nullptr, BB * TT, 3 * CC, CC);
    attn_fwd<<<1024, 256, 0, stream>>>(qb, kb, vtb, attb);
    gemm_bt<1><<<dim3(64, 8), 256, 0, stream>>>(attb, wprojb, bproj, nullptr,
                                                nullptr, nullptr, out, BB * TT,
                                                CC, CC);
}

// Round 18
// 184.227 us; speedup vs baseline: 1.0026x; 1.0026x over previous
//
#include <hip/hip_runtime.h>
#include <hip/hip_bf16.h>
#include <stdint.h>

// Problem constants
constexpr int BB = 4, TT = 2048, CC = 1024, HH = 16, DD = 64;

typedef __bf16 bf16_t;
typedef bf16_t bf16x8 __attribute__((ext_vector_type(8)));
typedef float f32x4 __attribute__((ext_vector_type(4)));

// Native cast: compiler emits v_cvt_pk_bf16_f32 for adjacent pairs (RNE).
__device__ __forceinline__ unsigned short f2bf(float f) {
    union { __bf16 h; unsigned short u; } v;
    v.h = (__bf16)f;
    return v.u;
}

__device__ __forceinline__ f32x4 mfma16(bf16x8 a, bf16x8 b, f32x4 c) {
    return __builtin_amdgcn_mfma_f32_16x16x32_bf16(a, b, c, 0, 0, 0);
}

#define LOAD_LDS16(g, l)                                                      \
    __builtin_amdgcn_global_load_lds(                                         \
        (const __attribute__((address_space(1))) void*)(g),                   \
        (__attribute__((address_space(3))) void*)(l), 16, 0, 0)

// ---------------- fused f32 -> bf16 convert for all 3 arrays ----------------
__global__ __launch_bounds__(256) void cvt_all(
    const float* __restrict__ a, long na,    // quads
    const float* __restrict__ b, long nb,    // quads
    const float* __restrict__ c, long nc,    // quads
    unsigned short* __restrict__ oa, unsigned short* __restrict__ ob,
    unsigned short* __restrict__ oc) {
    const long ntot = na + nb + nc;
    long i = (long)blockIdx.x * blockDim.x + threadIdx.x;
    const long stride = (long)gridDim.x * blockDim.x;
    for (; i < ntot; i += stride) {
        const float* src;
        unsigned short* dst;
        long q = i;
        if (q < na) { src = a; dst = oa; }
        else if (q < na + nb) { q -= na; src = b; dst = ob; }
        else { q -= na + nb; src = c; dst = oc; }
        float4 v = *(const float4*)(src + q * 4);
        ushort4 o;
        o.x = f2bf(v.x); o.y = f2bf(v.y); o.z = f2bf(v.z); o.w = f2bf(v.w);
        *(ushort4*)(dst + q * 4) = o;
    }
}

// ---------------- GEMM: C[m,n] = sum_k A[m,k]*Bw[n,k] + bias[n] ----------------
// m97 structure: 128x128 tile, BK=32, 4 waves, global_load_lds(16B), dbuf LDS.
// __launch_bounds__(256,3): pin 3 blocks/CU (R10-verified). Do not restructure
// the K-loop (R8/R11 deep-pipeline rewrites both lost at K=1024).
// MODE 0 epilogue: q scaled by 0.125*log2e (log2-domain softmax downstream).
//   which==2 (v) blocks: LDS-transpose epilogue (R16, -17 us total) —
//   coalesced 16B v^T stores via [2][64][136] d-major tile, chunk XOR c^=d&7.
// MODE 1: f32 out[m*N+n] (coalesced, direct).
template <int MODE>
__global__ __launch_bounds__(256, 3) void gemm_bt(
    const unsigned short* __restrict__ A,    // [M][K] bf16
    const unsigned short* __restrict__ Bw,   // [N][K] bf16
    const float* __restrict__ bias,          // [N]
    unsigned short* __restrict__ qb, unsigned short* __restrict__ kb,
    unsigned short* __restrict__ vtb, float* __restrict__ outf,
    int M, int N, int K) {
    __shared__ __align__(16) unsigned short smem[17408];
    unsigned short* Asb = smem;
    unsigned short* Bsb = smem + 8192;
    const int tid = threadIdx.x;
    const int w = tid >> 6, lane = tid & 63;
    const int g = lane >> 4, q16 = lane & 15;
    const int wr = w >> 1, wc = w & 1;
    const int mbase = blockIdx.x * 128;
    const int nbase = blockIdx.y * 128;
    const int srow = lane >> 2;
    const int scol = (lane & 3) * 8;

    f32x4 acc[4][4];
#pragma unroll
    for (int i = 0; i < 4; ++i)
#pragma unroll
        for (int j = 0; j < 4; ++j) acc[i][j] = (f32x4){0.f, 0.f, 0.f, 0.f};

    const int nk = K >> 5;

    auto stage = [&](int buf, int t) {
        const int k0 = t << 5;
#pragma unroll
        for (int ii = 0; ii < 2; ++ii) {
            const int i = w + ii * 4;
            const unsigned short* ga =
                A + (long)(mbase + i * 16 + srow) * K + k0 + scol;
            LOAD_LDS16(ga, &Asb[buf * 4096 + i * 512]);
            const unsigned short* gb =
                Bw + (long)(nbase + i * 16 + srow) * K + k0 + scol;
            LOAD_LDS16(gb, &Bsb[buf * 4096 + i * 512]);
        }
    };

    stage(0, 0);
    __syncthreads();
    int cur = 0;
    for (int t = 0; t < nk; ++t) {
        if (t + 1 < nk) stage(cur ^ 1, t + 1);
        bf16x8 af[4], bfr[4];
#pragma unroll
        for (int mi = 0; mi < 4; ++mi)
            af[mi] = *(const bf16x8*)&Asb[cur * 4096 +
                                          (wr * 64 + mi * 16 + q16) * 32 + 8 * g];
#pragma unroll
        for (int ni = 0; ni < 4; ++ni)
            bfr[ni] = *(const bf16x8*)&Bsb[cur * 4096 +
                                           (wc * 64 + ni * 16 + q16) * 32 + 8 * g];
#pragma unroll
        for (int mi = 0; mi < 4; ++mi)
#pragma unroll
            for (int ni = 0; ni < 4; ++ni)
                acc[mi][ni] = mfma16(af[mi], bfr[ni], acc[mi][ni]);
        __syncthreads();
        cur ^= 1;
    }

    if (MODE == 0 && (nbase >> 10) == 2) {
        // ---- v-block: LDS transpose epilogue (As/Bs dead after final barrier)
        const int bb = mbase >> 11, t0 = mbase & 2047;
        const int h0 = (nbase & 1023) >> 6;
#pragma unroll
        for (int mi = 0; mi < 4; ++mi) {
#pragma unroll
            for (int ni = 0; ni < 4; ++ni) {
                const int nl = wc * 64 + ni * 16 + q16;   // 0..127
                const int hh = nl >> 6, d = nl & 63;
                const float bv = bias[nbase + nl];
                ushort4 pk;
                pk.x = f2bf(acc[mi][ni][0] + bv);
                pk.y = f2bf(acc[mi][ni][1] + bv);
                pk.z = f2bf(acc[mi][ni][2] + bv);
                pk.w = f2bf(acc[mi][ni][3] + bv);
                const int tb = wr * 64 + mi * 16 + 4 * g;  // t' of r=0
                const int cp = (tb >> 3) ^ (d & 7);        // chunk XOR swizzle
                const int pos = cp * 8 + (tb & 7);
                *(ushort4*)&smem[hh * 8704 + d * 136 + pos] = pk;
            }
        }
        __syncthreads();
#pragma unroll
        for (int it = 0; it < 8; ++it) {
            const int task = it * 256 + tid;
            const int hh = task >> 10, d = (task >> 4) & 63, cr = task & 15;
            const int cp = cr ^ (d & 7);
            uint4 v4 = *(const uint4*)&smem[hh * 8704 + d * 136 + cp * 8];
            const long off =
                ((long)(bb * HH + h0 + hh) * DD + d) * TT + t0 + cr * 8;
            *(uint4*)&vtb[off] = v4;
        }
        return;
    }

#pragma unroll
    for (int mi = 0; mi < 4; ++mi) {
#pragma unroll
        for (int ni = 0; ni < 4; ++ni) {
            const int n = nbase + wc * 64 + ni * 16 + q16;
            const float bv = bias[n];
#pragma unroll
            for (int r = 0; r < 4; ++r) {
                const int m = mbase + wr * 64 + mi * 16 + 4 * g + r;
                const float val = acc[mi][ni][r] + bv;
                if (MODE == 0) {
                    const int rem = n & 1023;
                    const int h = rem >> 6, d = rem & 63;
                    const int b = m >> 11, t = m & 2047;
                    const long bh = (long)(b * HH + h);
                    if ((n >> 10) == 0)  // 0.125*log2e: log2-domain softmax
                        qb[(bh * TT + t) * DD + d] =
                            f2bf(val * 0.18033688011112042f);
                    else
                        kb[(bh * TT + t) * DD + d] = f2bf(val);
                } else {
                    outf[(long)m * N + n] = val;
                }
            }
        }
    }
}

// ------ causal flash attention (R16-exact: shfl-free common path) -----------
// grid: flat 2048 blocks, XCD-swizzled; LPT (bx = 31-(swz&31), longest first).
// Swapped QK^T, log2-domain softmax (Q pre-scaled by log2e), defer vote on
// in-lane max only, per-lane partial denominator (cross-lane sum once after
// the loop), source-XOR-swizzled gload_lds staging (dbuf), plds stride-64
// XOR, setprio on MFMA clusters, LDS 40960 B = 4 blocks/CU.
// R17's 2-set K/V amortization reverted: occupancy 27->17% cost more than
// halved LDS traffic gained (latency-hiding-bound; resident waves are the
// binding resource).
__global__ __launch_bounds__(256, 4) void attn_fwd(
    const unsigned short* __restrict__ qb, const unsigned short* __restrict__ kb,
    const unsigned short* __restrict__ vtb, unsigned short* __restrict__ attb) {
    __shared__ __align__(16) unsigned short Ks[2][64 * 64];
    __shared__ __align__(16) unsigned short Vs[2][64 * 64];
    __shared__ __align__(16) unsigned short plds[4][16 * 64];
    const int tid = threadIdx.x;
    const int w = tid >> 6, lane = tid & 63;
    const int g = lane >> 4, q16 = lane & 15;
    const int bid = blockIdx.x;
    const int swz = (bid & 7) * 256 + (bid >> 3);   // 2048 % 8 == 0: bijective
    const int bx = 31 - (swz & 31);                 // LPT: big bx first
    const int bh = swz >> 5;
    const int b = bh >> 4, h = bh & 15;
    const int qbase = bx * 64 + w * 16;

    const unsigned short* Q = qb + (long)bh * TT * DD;
    const unsigned short* Kp = kb + (long)bh * TT * DD;
    const unsigned short* Vt = vtb + (long)bh * DD * TT;

    const int srow = tid >> 3;                       // 0..31
    const int ssl = ((tid & 7) ^ (srow & 7)) * 8;    // swizzled col (shorts)
    unsigned short* kdst0 = &Ks[0][0] + w * 512;     // wave-uniform dests
    unsigned short* vdst0 = &Vs[0][0] + w * 512;

    auto stageKV = [&](int buf, int kt) {
        const long kb0 = (long)kt * 64;
        const unsigned short* gk = Kp + (kb0 + srow) * DD + ssl;
        const unsigned short* gv = Vt + (long)srow * TT + kb0 + ssl;
        unsigned short* kd = kdst0 + buf * 4096;
        unsigned short* vd = vdst0 + buf * 4096;
        LOAD_LDS16(gk, kd);
        LOAD_LDS16(gk + 32l * DD, kd + 2048);
        LOAD_LDS16(gv, vd);
        LOAD_LDS16(gv + 32l * TT, vd + 2048);
    };

    bf16x8 aq0 = *(const bf16x8*)&Q[(qbase + q16) * DD + 8 * g];
    bf16x8 aq1 = *(const bf16x8*)&Q[(qbase + q16) * DD + 32 + 8 * g];

    f32x4 acc[4];
#pragma unroll
    for (int i = 0; i < 4; ++i) acc[i] = (f32x4){0.f, 0.f, 0.f, 0.f};
    float mrow = -1e30f, lrow = 0.f;  // lrow: per-lane PARTIAL (16 k-slots)

    const int slot0 = (g ^ (q16 & 7)) << 3;
    const int nkt = bx + 1;
    stageKV(0, 0);
    __syncthreads();
    int cur = 0;
    for (int kt = 0; kt < nkt; ++kt) {
        if (kt + 1 < nkt) stageKV(cur ^ 1, kt + 1);
        const int kbase = kt * 64;
        f32x4 p[4];
#pragma unroll
        for (int s = 0; s < 4; ++s) p[s] = (f32x4){0.f, 0.f, 0.f, 0.f};
        __builtin_amdgcn_s_setprio(1);
#pragma unroll
        for (int s = 0; s < 4; ++s) {
            const int kr = (16 * s + q16) * 64;
            bf16x8 bk0 = *(const bf16x8*)&Ks[cur][kr + slot0];
            bf16x8 bk1 = *(const bf16x8*)&Ks[cur][kr + (slot0 ^ 32)];
            p[s] = mfma16(bk0, aq0, p[s]);
            p[s] = mfma16(bk1, aq1, p[s]);
        }
        __builtin_amdgcn_s_setprio(0);
        const int q = qbase + q16;
        if (kt == nkt - 1) {
#pragma unroll
            for (int s = 0; s < 4; ++s)
#pragma unroll
                for (int r = 0; r < 4; ++r)
                    if (kbase + 16 * s + 4 * g + r > q) p[s][r] = -1e30f;
        }
        // in-lane max only (no shfls)
        float t = fmaxf(fmaxf(p[0][0], p[0][1]), fmaxf(p[0][2], p[0][3]));
#pragma unroll
        for (int s = 1; s < 4; ++s)
            t = fmaxf(t, fmaxf(fmaxf(p[s][0], p[s][1]), fmaxf(p[s][2], p[s][3])));
        if (__all(t - mrow <= 11.541560327111708f)) {  // 8*log2e
            float ssum = 0.f;
#pragma unroll
            for (int s = 0; s < 4; ++s)
#pragma unroll
                for (int r = 0; r < 4; ++r) {
                    p[s][r] = __builtin_amdgcn_exp2f(p[s][r] - mrow);
                    ssum += p[s][r];
                }
            lrow += ssum;  // per-lane partial
        } else {
            t = fmaxf(t, __shfl_xor(t, 16));
            t = fmaxf(t, __shfl_xor(t, 32));
            const float nm = fmaxf(mrow, t);
            const float fs = __builtin_amdgcn_exp2f(mrow - nm);
            mrow = nm;
            float ssum = 0.f;
#pragma unroll
            for (int s = 0; s < 4; ++s)
#pragma unroll
                for (int r = 0; r < 4; ++r) {
                    p[s][r] = __builtin_amdgcn_exp2f(p[s][r] - nm);
                    ssum += p[s][r];
                }
            lrow = lrow * fs + ssum;  // fs row-uniform -> partials consistent
            float fr[4];
#pragma unroll
            for (int r = 0; r < 4; ++r) fr[r] = __shfl(fs, 4 * g + r);
#pragma unroll
            for (int ni = 0; ni < 4; ++ni)
#pragma unroll
                for (int r = 0; r < 4; ++r) acc[ni][r] *= fr[r];
        }
#pragma unroll
        for (int s = 0; s < 4; ++s) {
            ushort4 pk;
            pk.x = f2bf(p[s][0]); pk.y = f2bf(p[s][1]);
            pk.z = f2bf(p[s][2]); pk.w = f2bf(p[s][3]);
            const int Gp = ((2 * s + (g >> 1)) ^ (q16 & 7)) * 8 + (g & 1) * 4;
            *(ushort4*)&plds[w][q16 * 64 + Gp] = pk;
        }
        bf16x8 pa0 = *(const bf16x8*)&plds[w][q16 * 64 + slot0];
        bf16x8 pa1 = *(const bf16x8*)&plds[w][q16 * 64 + (slot0 ^ 32)];
        __builtin_amdgcn_s_setprio(1);
#pragma unroll
        for (int ni = 0; ni < 4; ++ni) {
            const int vr = (ni * 16 + q16) * 64;
            bf16x8 bv0 = *(const bf16x8*)&Vs[cur][vr + slot0];
            bf16x8 bv1 = *(const bf16x8*)&Vs[cur][vr + (slot0 ^ 32)];
            acc[ni] = mfma16(pa0, bv0, acc[ni]);
            acc[ni] = mfma16(pa1, bv1, acc[ni]);
        }
        __builtin_amdgcn_s_setprio(0);
        __syncthreads();
        cur ^= 1;
    }
    // one cross-lane denominator reduction for the whole kernel
    lrow += __shfl_xor(lrow, 16);
    lrow += __shfl_xor(lrow, 32);
    float inv[4];
#pragma unroll
    for (int r = 0; r < 4; ++r) inv[r] = 1.0f / __shfl(lrow, 4 * g + r);
#pragma unroll
    for (int ni = 0; ni < 4; ++ni)
#pragma unroll
        for (int r = 0; r < 4; ++r) {
            const int q = qbase + 4 * g + r;
            const int d = ni * 16 + q16;
            attb[(((long)b * TT + q) * HH + h) * DD + d] =
                f2bf(acc[ni][r] * inv[r]);
        }
}

extern "C" void kernel_launch(void* const* d_in, const int* in_sizes, int n_in,
                              void* d_out, int out_size, void* d_ws, size_t ws_size,
                              hipStream_t stream) {
    const float* x = (const float*)d_in[0];
    const float* Wqkv = (const float*)d_in[1];
    const float* bqkv = (const float*)d_in[2];
    const float* Wproj = (const float*)d_in[3];
    const float* bproj = (const float*)d_in[4];
    float* out = (float*)d_out;

    char* ws = (char*)d_ws;
    unsigned short* xb = (unsigned short*)(ws);                  // 16 MB (reused as attb)
    unsigned short* wqkvb = (unsigned short*)(ws + (16l << 20)); // 6 MB
    unsigned short* wprojb = (unsigned short*)(ws + (22l << 20));// 2 MB
    unsigned short* qb = (unsigned short*)(ws + (24l << 20));    // 16 MB
    unsigned short* kb = (unsigned short*)(ws + (40l << 20));    // 16 MB
    unsigned short* vtb = (unsigned short*)(ws + (56l << 20));   // 16 MB
    unsigned short* attb = xb;  // x dead after QKV GEMM; reuse

    cvt_all<<<2048, 256, 0, stream>>>(
        x, (long)BB * TT * CC / 4, Wqkv, (long)3 * CC * CC / 4, Wproj,
        (long)CC * CC / 4, xb, wqkvb, wprojb);

    gemm_bt<0><<<dim3(64, 24), 256, 0, stream>>>(xb, wqkvb, bqkv, qb, kb, vtb,
                                                 nullptr, BB * TT, 3 * CC, CC);
    attn_fwd<<<2048, 256, 0, stream>>>(qb, kb, vtb, attb);
    gemm_bt<1><<<dim3(64, 8), 256, 0, stream>>>(attb, wprojb, bproj, nullptr,
                                                nullptr, nullptr, out, BB * TT,
                                                CC, CC);
}